// Round 2
// baseline (817.569 us; speedup 1.0000x reference)
//
#include <hip/hip_runtime.h>

#define IN_DIM 512
#define OUT_DIM 32
#define KSTEPS 10
#define ALPHA 0.1f
#define SCB 512      // scan block chunk

typedef __attribute__((ext_vector_type(8))) short short8;    // 8 bf16 (4 VGPRs)
typedef __attribute__((ext_vector_type(4))) float floatx4;   // MFMA acc
typedef _Float16 fp16x8 __attribute__((ext_vector_type(8))); // 16B packed fp16

// ---------------- degree / norm / chunked-CSR build ----------------

__global__ void k_count(const int* __restrict__ src, const int* __restrict__ dst,
                        int* __restrict__ cnt, int E, int cdiv) {
    int e = blockIdx.x * blockDim.x + threadIdx.x;
    if (e < E) {
        int ch = src[e] / cdiv;
        atomicAdd(&cnt[dst[e] * 4 + ch], 1);
    }
}

__global__ void k_rsqrt(const int* __restrict__ cnt, float* __restrict__ dinv, int N) {
    int i = blockIdx.x * blockDim.x + threadIdx.x;
    if (i < N) {
        int d = cnt[4 * i] + cnt[4 * i + 1] + cnt[4 * i + 2] + cnt[4 * i + 3];
        dinv[i] = rsqrtf((float)d + 1.0f);  // +1 self-loop
    }
}

// ---------------- parallel exclusive scan (3 phases) ----------------

__global__ __launch_bounds__(SCB) void k_bsum(const int* __restrict__ v,
                                              int* __restrict__ bsum, int M) {
    __shared__ int s[SCB];
    int i = blockIdx.x * SCB + threadIdx.x;
    s[threadIdx.x] = (i < M) ? v[i] : 0;
    __syncthreads();
    for (int d = SCB / 2; d > 0; d >>= 1) {
        if (threadIdx.x < d) s[threadIdx.x] += s[threadIdx.x + d];
        __syncthreads();
    }
    if (threadIdx.x == 0) bsum[blockIdx.x] = s[0];
}

__global__ __launch_bounds__(1024) void k_bscan(const int* __restrict__ bsum,
                                                int* __restrict__ bsum_off,
                                                int* __restrict__ total_out, int NB) {
    __shared__ int s[1024];
    int t = threadIdx.x;
    s[t] = (t < NB) ? bsum[t] : 0;
    __syncthreads();
    for (int d = 1; d < 1024; d <<= 1) {
        int v = (t >= d) ? s[t - d] : 0;
        __syncthreads();
        s[t] += v;
        __syncthreads();
    }
    if (t < NB) bsum_off[t] = (t == 0) ? 0 : s[t - 1];
    if (t == 0 && total_out) *total_out = s[1023];
}

__global__ __launch_bounds__(SCB) void k_boff(const int* __restrict__ v,
                                              const int* __restrict__ bsum_off,
                                              int* __restrict__ off, int M) {
    __shared__ int s[SCB];
    int t = threadIdx.x;
    int i = blockIdx.x * SCB + t;
    int myv = (i < M) ? v[i] : 0;
    s[t] = myv;
    __syncthreads();
    for (int d = 1; d < SCB; d <<= 1) {
        int u = (t >= d) ? s[t - d] : 0;
        __syncthreads();
        s[t] += u;
        __syncthreads();
    }
    if (i < M) off[i] = bsum_off[blockIdx.x] + s[t] - myv;  // exclusive
}

__global__ void k_fill(const int* __restrict__ src, const int* __restrict__ dst,
                       const float* __restrict__ dinv, const int* __restrict__ off4,
                       int* __restrict__ cur, float2* __restrict__ csr, int E, int cdiv) {
    int e = blockIdx.x * blockDim.x + threadIdx.x;
    if (e < E) {
        int d = dst[e], s = src[e];
        int key = d * 4 + s / cdiv;
        int pos = off4[key] + atomicAdd(&cur[key], 1);
        csr[pos] = make_float2(dinv[s] * dinv[d], __int_as_float(s));
    }
}

// ---------------- bf16 split helpers ----------------

__device__ inline unsigned bf16_rne(float f) {
    unsigned u = __float_as_uint(f);
    return (u + 0x7FFFu + ((u >> 16) & 1u)) >> 16;
}

__global__ void k_wsplit(const float* __restrict__ W, short* __restrict__ Wh,
                         short* __restrict__ Wl, int M) {
    int i = blockIdx.x * blockDim.x + threadIdx.x;
    if (i < M) {
        float f = W[i];
        unsigned hb = bf16_rne(f);
        float fh = __uint_as_float(hb << 16);
        unsigned lb = bf16_rne(f - fh);
        Wh[i] = (short)hb;
        Wl[i] = (short)lb;
    }
}

__device__ inline void split8v(float4 v0, float4 v1, short8& hi, short8& lo) {
    float f[8] = {v0.x, v0.y, v0.z, v0.w, v1.x, v1.y, v1.z, v1.w};
#pragma unroll
    for (int j = 0; j < 8; j++) {
        unsigned hb = bf16_rne(f[j]);
        float fh = __uint_as_float(hb << 16);
        unsigned lb = bf16_rne(f[j] - fh);
        hi[j] = (short)hb;
        lo[j] = (short)lb;
    }
}

// ---------------- dense projection: LDS-staged bf16-split MFMA ----------------
// 64 nodes/block, K consumed in 4 chunks of 128 cols.
// Stage: coalesced (32 lanes = contiguous 512B per row-segment), 8x16B/thread
//        in flight, XOR-swizzled LDS writes (byte ^= (row&7)<<4).
// Async-stage split (T14): chunk c+1's global loads are issued before
// consuming chunk c, so HBM latency hides under split+MFMA.
// Consume: ds_read_b128 pairs (swizzle -> 2-way max, free), 6 MFMA per kc.

__global__ __launch_bounds__(256) void k_gemm4(const float* __restrict__ x,
                                               const short* __restrict__ Wh,
                                               const short* __restrict__ Wl,
                                               const float* __restrict__ bias,
                                               float* __restrict__ h,
                                               _Float16* __restrict__ z0, int N) {
    __shared__ float lds[64 * 128];  // 32 KB
    const int t = threadIdx.x;
    const int wave = t >> 6, lane = t & 63;
    const int m = lane & 15, quad = lane >> 4;
    const int rowBase = blockIdx.x * 64;
    const int sr = t >> 5;   // 0..7  (stage row within group of 8)
    const int sw = t & 31;   // 0..31 (16B segment within 512B row-chunk)

    // clamped source rows for staging (loads only; stores are guarded)
    int rows[8];
#pragma unroll
    for (int i = 0; i < 8; i++) {
        int rr = rowBase + i * 8 + sr;
        rows[i] = (rr < N) ? rr : (N - 1);
    }

    const short* w0h = Wh + (size_t)m * IN_DIM + quad * 8;          // outs 0..15
    const short* w0l = Wl + (size_t)m * IN_DIM + quad * 8;
    const short* w1h = Wh + (size_t)(m + 16) * IN_DIM + quad * 8;   // outs 16..31
    const short* w1l = Wl + (size_t)(m + 16) * IN_DIM + quad * 8;

    floatx4 acc0 = {0.f, 0.f, 0.f, 0.f};
    floatx4 acc1 = {0.f, 0.f, 0.f, 0.f};

    auto loadch = [&](float4* dstp, int ch) {
#pragma unroll
        for (int i = 0; i < 8; i++)
            dstp[i] = *(const float4*)(x + (size_t)rows[i] * IN_DIM + ch * 128 + sw * 4);
    };
    auto writech = [&](const float4* rp) {
#pragma unroll
        for (int i = 0; i < 8; i++) {
            int row = i * 8 + sr;
            int bo = (row * 512 + sw * 16) ^ ((row & 7) << 4);
            *(float4*)((char*)lds + bo) = rp[i];
        }
    };
    auto consume = [&](int ch) {
        const int key = (m & 7) << 4;
        const int rbase = (wave * 16 + m) * 512;
#pragma unroll
        for (int kc = 0; kc < 4; kc++) {
            int rbyte = rbase + kc * 128 + quad * 32;
            float4 v0 = *(const float4*)((char*)lds + (rbyte ^ key));
            float4 v1 = *(const float4*)((char*)lds + ((rbyte + 16) ^ key));
            short8 Ah, Al;
            split8v(v0, v1, Ah, Al);
            int ko = ch * 128 + kc * 32;
            short8 B0h = *(const short8*)(w0h + ko);
            short8 B0l = *(const short8*)(w0l + ko);
            short8 B1h = *(const short8*)(w1h + ko);
            short8 B1l = *(const short8*)(w1l + ko);
            acc0 = __builtin_amdgcn_mfma_f32_16x16x32_bf16(Ah, B0h, acc0, 0, 0, 0);
            acc1 = __builtin_amdgcn_mfma_f32_16x16x32_bf16(Ah, B1h, acc1, 0, 0, 0);
            acc0 = __builtin_amdgcn_mfma_f32_16x16x32_bf16(Al, B0h, acc0, 0, 0, 0);
            acc1 = __builtin_amdgcn_mfma_f32_16x16x32_bf16(Al, B1h, acc1, 0, 0, 0);
            acc0 = __builtin_amdgcn_mfma_f32_16x16x32_bf16(Ah, B0l, acc0, 0, 0, 0);
            acc1 = __builtin_amdgcn_mfma_f32_16x16x32_bf16(Ah, B1l, acc1, 0, 0, 0);
        }
    };

    float4 r[8], rn[8];
    loadch(r, 0);
#pragma unroll
    for (int ch = 0; ch < 4; ch++) {
        writech(r);
        __syncthreads();
        if (ch < 3) loadch(rn, ch + 1);  // issue next-chunk loads BEFORE compute
        consume(ch);
        __syncthreads();
        if (ch < 3) {
#pragma unroll
            for (int i = 0; i < 8; i++) r[i] = rn[i];
        }
    }

    // C/D layout: col = lane&15 (out), row = quad*4 + reg (node)
    float b0 = bias[m], b1 = bias[16 + m];
    int nodeBase = rowBase + wave * 16;
#pragma unroll
    for (int rr2 = 0; rr2 < 4; rr2++) {
        int node = nodeBase + quad * 4 + rr2;
        if (node < N) {
            float v0 = acc0[rr2] + b0;
            float v1 = acc1[rr2] + b1;
            h[(size_t)node * OUT_DIM + m]       = v0;
            h[(size_t)node * OUT_DIM + 16 + m]  = v1;
            z0[(size_t)node * OUT_DIM + m]      = (_Float16)v0;
            z0[(size_t)node * OUT_DIM + 16 + m] = (_Float16)v1;
        }
    }
}

// ---------------- propagation: pull, fp16 z, 4 lanes/node x 8ch ----------------
// 4 lanes per dst node; lane owns 8 channels (16B fp16 loads). Halves the
// load-instruction count vs 8x4 and halves wave count. Unroll x4 for MLP.
// Last step writes fp32 to d_out (no fp16 rounding on final output).

__global__ __launch_bounds__(256) void k_pull(const int* __restrict__ off4,
                                              const float2* __restrict__ csr,
                                              const _Float16* __restrict__ zprev,
                                              const float* __restrict__ h,
                                              const float* __restrict__ dinv,
                                              _Float16* __restrict__ znext,
                                              float* __restrict__ outF, int N) {
    int t = blockIdx.x * 256 + threadIdx.x;
    int node = t >> 2;
    int l = (t & 3) * 8;
    if (node >= N) return;
    int beg = off4[node * 4];
    int end = off4[node * 4 + 4];
    float a0[8], a1[8];
#pragma unroll
    for (int c = 0; c < 8; c++) { a0[c] = 0.f; a1[c] = 0.f; }
    int j = beg;
    for (; j + 4 <= end; j += 4) {
        float2 e0 = csr[j];
        float2 e1 = csr[j + 1];
        float2 e2 = csr[j + 2];
        float2 e3 = csr[j + 3];
        fp16x8 za = *(const fp16x8*)(zprev + (size_t)__float_as_int(e0.y) * OUT_DIM + l);
        fp16x8 zb = *(const fp16x8*)(zprev + (size_t)__float_as_int(e1.y) * OUT_DIM + l);
        fp16x8 zc = *(const fp16x8*)(zprev + (size_t)__float_as_int(e2.y) * OUT_DIM + l);
        fp16x8 zd = *(const fp16x8*)(zprev + (size_t)__float_as_int(e3.y) * OUT_DIM + l);
#pragma unroll
        for (int c = 0; c < 8; c++) {
            a0[c] = fmaf(e0.x, (float)za[c], a0[c]);
            a1[c] = fmaf(e1.x, (float)zb[c], a1[c]);
            a0[c] = fmaf(e2.x, (float)zc[c], a0[c]);
            a1[c] = fmaf(e3.x, (float)zd[c], a1[c]);
        }
    }
    for (; j < end; j++) {
        float2 e = csr[j];
        fp16x8 z = *(const fp16x8*)(zprev + (size_t)__float_as_int(e.y) * OUT_DIM + l);
#pragma unroll
        for (int c = 0; c < 8; c++) a0[c] = fmaf(e.x, (float)z[c], a0[c]);
    }
    float d = dinv[node];
    float d2 = d * d;
    fp16x8 zs = *(const fp16x8*)(zprev + (size_t)node * OUT_DIM + l);
    float4 h0 = *(const float4*)(h + (size_t)node * OUT_DIM + l);
    float4 h1 = *(const float4*)(h + (size_t)node * OUT_DIM + l + 4);
    float hh[8] = {h0.x, h0.y, h0.z, h0.w, h1.x, h1.y, h1.z, h1.w};
    float rr[8];
#pragma unroll
    for (int c = 0; c < 8; c++) {
        float s = (a0[c] + a1[c]) + d2 * (float)zs[c];
        rr[c] = fmaf(1.0f - ALPHA, s, ALPHA * hh[c]);
    }
    if (outF) {
        *(float4*)(outF + (size_t)node * OUT_DIM + l)     = make_float4(rr[0], rr[1], rr[2], rr[3]);
        *(float4*)(outF + (size_t)node * OUT_DIM + l + 4) = make_float4(rr[4], rr[5], rr[6], rr[7]);
    } else {
        fp16x8 o;
#pragma unroll
        for (int c = 0; c < 8; c++) o[c] = (_Float16)rr[c];
        *(fp16x8*)(znext + (size_t)node * OUT_DIM + l) = o;
    }
}

extern "C" void kernel_launch(void* const* d_in, const int* in_sizes, int n_in,
                              void* d_out, int out_size, void* d_ws, size_t ws_size,
                              hipStream_t stream) {
    const float* x    = (const float*)d_in[0];
    const float* W    = (const float*)d_in[1];
    const float* bias = (const float*)d_in[2];
    const int*   ei   = (const int*)d_in[3];

    const int N = in_sizes[0] / IN_DIM;   // 100000
    const int E = in_sizes[3] / 2;        // 1600000
    const int* src = ei;
    const int* dst = ei + E;
    const int cdiv = (N + 3) / 4;
    const int M = 4 * N;                  // scan length
    const int NB = (M + SCB - 1) / SCB;   // 782 <= 1024
    const int WM = OUT_DIM * IN_DIM;      // 16384

    // workspace layout
    char* ws = (char*)d_ws;
    size_t o = 0;
    float*     h    = (float*)(ws + o);     o += (size_t)N * OUT_DIM * 4;  // 12.8 MB
    _Float16*  zA   = (_Float16*)(ws + o);  o += (size_t)N * OUT_DIM * 2;  // 6.4 MB
    _Float16*  zB   = (_Float16*)(ws + o);  o += (size_t)N * OUT_DIM * 2;  // 6.4 MB
    float2*    csr  = (float2*)(ws + o);    o += (size_t)E * 8;            // 12.8 MB
    float*     dinv = (float*)(ws + o);     o += (size_t)N * 4;
    int*       off4 = (int*)(ws + o);       o += (size_t)(M + 1) * 4;
    int*       cnt  = (int*)(ws + o);       o += (size_t)M * 4;
    int*       cur  = (int*)(ws + o);       o += (size_t)M * 4;
    int*       bsum = (int*)(ws + o);       o += (size_t)NB * 4;
    int*       boff = (int*)(ws + o);       o += (size_t)NB * 4;
    short*     Wh   = (short*)(ws + o);     o += (size_t)WM * 2;
    short*     Wl   = (short*)(ws + o);     o += (size_t)WM * 2;

    const int B = 256;
    int gN = (N + B - 1) / B;
    int gE = (E + B - 1) / B;
    int gP = ((size_t)N * 4 + B - 1) / B;   // pull grid (1563)
    int gG = (N + 63) / 64;                 // gemm grid (1563)
    int gW = (WM + B - 1) / B;

    hipMemsetAsync(cnt, 0, (size_t)2 * M * 4, stream);  // cnt + cur (adjacent)

    // degree + norm + chunked CSR
    k_count<<<gE, B, 0, stream>>>(src, dst, cnt, E, cdiv);
    k_rsqrt<<<gN, B, 0, stream>>>(cnt, dinv, N);
    k_bsum<<<NB, SCB, 0, stream>>>(cnt, bsum, M);
    k_bscan<<<1, 1024, 0, stream>>>(bsum, boff, off4 + M, NB);
    k_boff<<<NB, SCB, 0, stream>>>(cnt, boff, off4, M);
    k_fill<<<gE, B, 0, stream>>>(src, dst, dinv, off4, cur, csr, E, cdiv);

    // W bf16-split (once) + dense projection (h fp32 + z0 fp16 seed)
    k_wsplit<<<gW, B, 0, stream>>>(W, Wh, Wl, WM);
    k_gemm4<<<gG, B, 0, stream>>>(x, Wh, Wl, bias, h, zA, N);

    // K propagation steps in fp16; final step writes fp32 directly to d_out
    for (int s = 0; s < KSTEPS; s++) {
        const _Float16* zprev = (s % 2 == 0) ? zA : zB;
        _Float16* znext = (s % 2 == 0) ? zB : zA;
        float* outF = (s == KSTEPS - 1) ? (float*)d_out : nullptr;
        k_pull<<<gP, B, 0, stream>>>(off4, csr, zprev, h, dinv, znext, outF, N);
    }
}

// Round 3
// 702.082 us; speedup vs baseline: 1.1645x; 1.1645x over previous
//
#include <hip/hip_runtime.h>

#define IN_DIM 512
#define OUT_DIM 32
#define KSTEPS 10
#define ALPHA 0.1f
#define SCB 512      // scan block chunk

typedef __attribute__((ext_vector_type(8))) short short8;    // 8 bf16 (4 VGPRs)
typedef __attribute__((ext_vector_type(4))) float floatx4;   // MFMA acc
typedef _Float16 fp16x8 __attribute__((ext_vector_type(8))); // 16B packed fp16

// ---------------- degree / norm / chunked-CSR build ----------------

__global__ void k_count(const int* __restrict__ src, const int* __restrict__ dst,
                        int* __restrict__ cnt, int E, int cdiv) {
    int e = blockIdx.x * blockDim.x + threadIdx.x;
    if (e < E) {
        int ch = src[e] / cdiv;
        atomicAdd(&cnt[dst[e] * 4 + ch], 1);
    }
}

__global__ void k_rsqrt(const int* __restrict__ cnt, float* __restrict__ dinv, int N) {
    int i = blockIdx.x * blockDim.x + threadIdx.x;
    if (i < N) {
        int d = cnt[4 * i] + cnt[4 * i + 1] + cnt[4 * i + 2] + cnt[4 * i + 3];
        dinv[i] = rsqrtf((float)d + 1.0f);  // +1 self-loop
    }
}

// ---------------- parallel exclusive scan (3 phases) ----------------

__global__ __launch_bounds__(SCB) void k_bsum(const int* __restrict__ v,
                                              int* __restrict__ bsum, int M) {
    __shared__ int s[SCB];
    int i = blockIdx.x * SCB + threadIdx.x;
    s[threadIdx.x] = (i < M) ? v[i] : 0;
    __syncthreads();
    for (int d = SCB / 2; d > 0; d >>= 1) {
        if (threadIdx.x < d) s[threadIdx.x] += s[threadIdx.x + d];
        __syncthreads();
    }
    if (threadIdx.x == 0) bsum[blockIdx.x] = s[0];
}

__global__ __launch_bounds__(1024) void k_bscan(const int* __restrict__ bsum,
                                                int* __restrict__ bsum_off,
                                                int* __restrict__ total_out, int NB) {
    __shared__ int s[1024];
    int t = threadIdx.x;
    s[t] = (t < NB) ? bsum[t] : 0;
    __syncthreads();
    for (int d = 1; d < 1024; d <<= 1) {
        int v = (t >= d) ? s[t - d] : 0;
        __syncthreads();
        s[t] += v;
        __syncthreads();
    }
    if (t < NB) bsum_off[t] = (t == 0) ? 0 : s[t - 1];
    if (t == 0 && total_out) *total_out = s[1023];
}

__global__ __launch_bounds__(SCB) void k_boff(const int* __restrict__ v,
                                              const int* __restrict__ bsum_off,
                                              int* __restrict__ off, int M) {
    __shared__ int s[SCB];
    int t = threadIdx.x;
    int i = blockIdx.x * SCB + t;
    int myv = (i < M) ? v[i] : 0;
    s[t] = myv;
    __syncthreads();
    for (int d = 1; d < SCB; d <<= 1) {
        int u = (t >= d) ? s[t - d] : 0;
        __syncthreads();
        s[t] += u;
        __syncthreads();
    }
    if (i < M) off[i] = bsum_off[blockIdx.x] + s[t] - myv;  // exclusive
}

__global__ void k_fill(const int* __restrict__ src, const int* __restrict__ dst,
                       const float* __restrict__ dinv, const int* __restrict__ off4,
                       int* __restrict__ cur, float2* __restrict__ csr, int E, int cdiv) {
    int e = blockIdx.x * blockDim.x + threadIdx.x;
    if (e < E) {
        int d = dst[e], s = src[e];
        int key = d * 4 + s / cdiv;
        int pos = off4[key] + atomicAdd(&cur[key], 1);
        csr[pos] = make_float2(dinv[s] * dinv[d], __int_as_float(s));
    }
}

// ---------------- bf16 split helpers ----------------

__device__ inline unsigned bf16_rne(float f) {
    unsigned u = __float_as_uint(f);
    return (u + 0x7FFFu + ((u >> 16) & 1u)) >> 16;
}

__global__ void k_wsplit(const float* __restrict__ W, short* __restrict__ Wh,
                         short* __restrict__ Wl, int M) {
    int i = blockIdx.x * blockDim.x + threadIdx.x;
    if (i < M) {
        float f = W[i];
        unsigned hb = bf16_rne(f);
        float fh = __uint_as_float(hb << 16);
        unsigned lb = bf16_rne(f - fh);
        Wh[i] = (short)hb;
        Wl[i] = (short)lb;
    }
}

__device__ inline void split8v(float4 v0, float4 v1, short8& hi, short8& lo) {
    float f0 = v0.x, f1 = v0.y, f2 = v0.z, f3 = v0.w;
    float f4 = v1.x, f5 = v1.y, f6 = v1.z, f7 = v1.w;
    float fv[8] = {f0, f1, f2, f3, f4, f5, f6, f7};
#pragma unroll
    for (int j = 0; j < 8; j++) {
        unsigned hb = bf16_rne(fv[j]);
        float fh = __uint_as_float(hb << 16);
        unsigned lb = bf16_rne(fv[j] - fh);
        hi[j] = (short)hb;
        lo[j] = (short)lb;
    }
}

// ---------------- dense projection: LDS-staged bf16-split MFMA ----------------
// 64 nodes/block, 4 waves; wave w owns rows [w*16, w*16+16) end-to-end:
// it stages them (coalesced 2x512B per load instr) AND consumes them ->
// NO cross-wave LDS sharing -> zero __syncthreads, single 32KB buffer.
// Staging values live in NAMED registers n0..n7 (round-2 lesson: arrays
// passed through lambdas escaped to scratch -> 368MB WRITE_SIZE).
// T14 async split: chunk ch+1 global loads issued before consume(ch);
// ds_writes after (DS ops are in-order per wave; compiler inserts vmcnt).
// XOR swizzle byte ^= (row&7)<<4 on both write and read (bijective).

__global__ __launch_bounds__(256) void k_gemm5(const float* __restrict__ x,
                                               const short* __restrict__ Wh,
                                               const short* __restrict__ Wl,
                                               const float* __restrict__ bias,
                                               float* __restrict__ h,
                                               _Float16* __restrict__ z0, int N) {
    __shared__ float lds[64 * 128];  // 32 KB, per-wave partitioned
    const int t = threadIdx.x;
    const int wave = t >> 6, lane = t & 63;
    const int m = lane & 15, quad = lane >> 4;
    const int rowBase = blockIdx.x * 64;
    const int ls = lane >> 5;   // 0..1: which of the 2 rows this half-wave stages
    const int sw = lane & 31;   // 16B segment within a 512B row-chunk

    // global byte offsets of the 8 rows this thread stages (wave-local rows
    // w*16 + i*2 + ls), clamped to N-1 (loads only; C-writes are guarded)
    int ro0, ro1, ro2, ro3, ro4, ro5, ro6, ro7;
    {
        int r;
#define MKRO(i, v)                                                  \
        r = rowBase + wave * 16 + (i) * 2 + ls;                     \
        if (r >= N) r = N - 1;                                      \
        v = r * (IN_DIM * 4);
        MKRO(0, ro0) MKRO(1, ro1) MKRO(2, ro2) MKRO(3, ro3)
        MKRO(4, ro4) MKRO(5, ro5) MKRO(6, ro6) MKRO(7, ro7)
#undef MKRO
    }
    const char* xbase = (const char*)x + sw * 16;

    // LDS write byte offsets (swizzled), one per staged row
    char* lwb = (char*)lds;
    int wo0, wo1, wo2, wo3, wo4, wo5, wo6, wo7;
    {
        int lr;
#define MKWO(i, v)                                                  \
        lr = wave * 16 + (i) * 2 + ls;                              \
        v = lr * 512 + ((sw * 16) ^ ((lr & 7) << 4));
        MKWO(0, wo0) MKWO(1, wo1) MKWO(2, wo2) MKWO(3, wo3)
        MKWO(4, wo4) MKWO(5, wo5) MKWO(6, wo6) MKWO(7, wo7)
#undef MKWO
    }

    // LDS read bases (swizzled) for the MFMA A-fragments
    const int key = (m & 7) << 4;
    const char* ra0 = (const char*)lds + (wave * 16 + m) * 512 + ((quad * 32) ^ key);
    const char* ra1 = (const char*)lds + (wave * 16 + m) * 512 + ((quad * 32 + 16) ^ key);

    const short* w0h = Wh + (size_t)m * IN_DIM + quad * 8;          // outs 0..15
    const short* w0l = Wl + (size_t)m * IN_DIM + quad * 8;
    const short* w1h = Wh + (size_t)(m + 16) * IN_DIM + quad * 8;   // outs 16..31
    const short* w1l = Wl + (size_t)(m + 16) * IN_DIM + quad * 8;

    floatx4 acc0 = {0.f, 0.f, 0.f, 0.f};
    floatx4 acc1 = {0.f, 0.f, 0.f, 0.f};

    float4 n0, n1, n2, n3, n4, n5, n6, n7;

#define LOADCH(ch) do {                                             \
        const char* xb = xbase + (ch) * 512;                        \
        n0 = *(const float4*)(xb + ro0);                            \
        n1 = *(const float4*)(xb + ro1);                            \
        n2 = *(const float4*)(xb + ro2);                            \
        n3 = *(const float4*)(xb + ro3);                            \
        n4 = *(const float4*)(xb + ro4);                            \
        n5 = *(const float4*)(xb + ro5);                            \
        n6 = *(const float4*)(xb + ro6);                            \
        n7 = *(const float4*)(xb + ro7);                            \
    } while (0)

#define DSWRITE() do {                                              \
        *(float4*)(lwb + wo0) = n0;                                 \
        *(float4*)(lwb + wo1) = n1;                                 \
        *(float4*)(lwb + wo2) = n2;                                 \
        *(float4*)(lwb + wo3) = n3;                                 \
        *(float4*)(lwb + wo4) = n4;                                 \
        *(float4*)(lwb + wo5) = n5;                                 \
        *(float4*)(lwb + wo6) = n6;                                 \
        *(float4*)(lwb + wo7) = n7;                                 \
    } while (0)

#define CONSUME(ch) do {                                            \
        _Pragma("unroll")                                           \
        for (int kc = 0; kc < 4; kc++) {                            \
            float4 v0 = *(const float4*)(ra0 + kc * 128);           \
            float4 v1 = *(const float4*)(ra1 + kc * 128);           \
            short8 Ah, Al;                                          \
            split8v(v0, v1, Ah, Al);                                \
            const int ko = (ch) * 128 + kc * 32;                    \
            short8 B0h = *(const short8*)(w0h + ko);                \
            short8 B0l = *(const short8*)(w0l + ko);                \
            short8 B1h = *(const short8*)(w1h + ko);                \
            short8 B1l = *(const short8*)(w1l + ko);                \
            acc0 = __builtin_amdgcn_mfma_f32_16x16x32_bf16(Ah, B0h, acc0, 0, 0, 0); \
            acc1 = __builtin_amdgcn_mfma_f32_16x16x32_bf16(Ah, B1h, acc1, 0, 0, 0); \
            acc0 = __builtin_amdgcn_mfma_f32_16x16x32_bf16(Al, B0h, acc0, 0, 0, 0); \
            acc1 = __builtin_amdgcn_mfma_f32_16x16x32_bf16(Al, B1h, acc1, 0, 0, 0); \
            acc0 = __builtin_amdgcn_mfma_f32_16x16x32_bf16(Ah, B0l, acc0, 0, 0, 0); \
            acc1 = __builtin_amdgcn_mfma_f32_16x16x32_bf16(Ah, B1l, acc1, 0, 0, 0); \
        }                                                           \
    } while (0)

    LOADCH(0);
    DSWRITE();
    LOADCH(1);     // in flight during consume(0)
    CONSUME(0);
    DSWRITE();
    LOADCH(2);
    CONSUME(1);
    DSWRITE();
    LOADCH(3);
    CONSUME(2);
    DSWRITE();
    CONSUME(3);

#undef LOADCH
#undef DSWRITE
#undef CONSUME

    // C/D layout: col = lane&15 (out), row = quad*4 + reg (node)
    float b0 = bias[m], b1 = bias[16 + m];
    int nodeBase = rowBase + wave * 16;
#pragma unroll
    for (int rr2 = 0; rr2 < 4; rr2++) {
        int node = nodeBase + quad * 4 + rr2;
        if (node < N) {
            float v0 = acc0[rr2] + b0;
            float v1 = acc1[rr2] + b1;
            h[(size_t)node * OUT_DIM + m]       = v0;
            h[(size_t)node * OUT_DIM + 16 + m]  = v1;
            z0[(size_t)node * OUT_DIM + m]      = (_Float16)v0;
            z0[(size_t)node * OUT_DIM + 16 + m] = (_Float16)v1;
        }
    }
}

// ---------------- propagation: pull, fp16 z, 4 lanes/node x 8ch ----------------
// 4 lanes per dst node; lane owns 8 channels (16B fp16 loads).
// csr entries loaded COALESCED (each lane one of 4 consecutive edges, 32B
// per group) then broadcast via __shfl within the aligned 4-lane group —
// removes the 4x redundant csr gathers. Group is convergent (shared beg/end).
// Last step writes fp32 to d_out.

__global__ __launch_bounds__(256) void k_pull(const int* __restrict__ off4,
                                              const float2* __restrict__ csr,
                                              const _Float16* __restrict__ zprev,
                                              const float* __restrict__ h,
                                              const float* __restrict__ dinv,
                                              _Float16* __restrict__ znext,
                                              float* __restrict__ outF, int N) {
    int t = blockIdx.x * 256 + threadIdx.x;
    int node = t >> 2;
    int sub = t & 3;
    int lane = threadIdx.x & 63;
    int gbase = lane & ~3;
    int l = sub * 8;
    if (node >= N) return;
    int beg = off4[node * 4];
    int end = off4[node * 4 + 4];
    float a0[8], a1[8];
#pragma unroll
    for (int c = 0; c < 8; c++) { a0[c] = 0.f; a1[c] = 0.f; }
    int j = beg;
    for (; j + 4 <= end; j += 4) {
        float2 e = csr[j + sub];              // coalesced: 4 lanes = 32B
        int   es = __float_as_int(e.y);
        float w0 = __shfl(e.x, gbase + 0);
        float w1 = __shfl(e.x, gbase + 1);
        float w2 = __shfl(e.x, gbase + 2);
        float w3 = __shfl(e.x, gbase + 3);
        int   s0 = __shfl(es, gbase + 0);
        int   s1 = __shfl(es, gbase + 1);
        int   s2 = __shfl(es, gbase + 2);
        int   s3 = __shfl(es, gbase + 3);
        fp16x8 za = *(const fp16x8*)(zprev + (size_t)s0 * OUT_DIM + l);
        fp16x8 zb = *(const fp16x8*)(zprev + (size_t)s1 * OUT_DIM + l);
        fp16x8 zc = *(const fp16x8*)(zprev + (size_t)s2 * OUT_DIM + l);
        fp16x8 zd = *(const fp16x8*)(zprev + (size_t)s3 * OUT_DIM + l);
#pragma unroll
        for (int c = 0; c < 8; c++) {
            a0[c] = fmaf(w0, (float)za[c], a0[c]);
            a1[c] = fmaf(w1, (float)zb[c], a1[c]);
            a0[c] = fmaf(w2, (float)zc[c], a0[c]);
            a1[c] = fmaf(w3, (float)zd[c], a1[c]);
        }
    }
    for (; j < end; j++) {
        float2 e = csr[j];
        fp16x8 z = *(const fp16x8*)(zprev + (size_t)__float_as_int(e.y) * OUT_DIM + l);
#pragma unroll
        for (int c = 0; c < 8; c++) a0[c] = fmaf(e.x, (float)z[c], a0[c]);
    }
    float d = dinv[node];
    float d2 = d * d;
    fp16x8 zs = *(const fp16x8*)(zprev + (size_t)node * OUT_DIM + l);
    float4 h0 = *(const float4*)(h + (size_t)node * OUT_DIM + l);
    float4 h1 = *(const float4*)(h + (size_t)node * OUT_DIM + l + 4);
    float hh[8] = {h0.x, h0.y, h0.z, h0.w, h1.x, h1.y, h1.z, h1.w};
    float rr[8];
#pragma unroll
    for (int c = 0; c < 8; c++) {
        float s = (a0[c] + a1[c]) + d2 * (float)zs[c];
        rr[c] = fmaf(1.0f - ALPHA, s, ALPHA * hh[c]);
    }
    if (outF) {
        *(float4*)(outF + (size_t)node * OUT_DIM + l)     = make_float4(rr[0], rr[1], rr[2], rr[3]);
        *(float4*)(outF + (size_t)node * OUT_DIM + l + 4) = make_float4(rr[4], rr[5], rr[6], rr[7]);
    } else {
        fp16x8 o;
#pragma unroll
        for (int c = 0; c < 8; c++) o[c] = (_Float16)rr[c];
        *(fp16x8*)(znext + (size_t)node * OUT_DIM + l) = o;
    }
}

extern "C" void kernel_launch(void* const* d_in, const int* in_sizes, int n_in,
                              void* d_out, int out_size, void* d_ws, size_t ws_size,
                              hipStream_t stream) {
    const float* x    = (const float*)d_in[0];
    const float* W    = (const float*)d_in[1];
    const float* bias = (const float*)d_in[2];
    const int*   ei   = (const int*)d_in[3];

    const int N = in_sizes[0] / IN_DIM;   // 100000
    const int E = in_sizes[3] / 2;        // 1600000
    const int* src = ei;
    const int* dst = ei + E;
    const int cdiv = (N + 3) / 4;
    const int M = 4 * N;                  // scan length
    const int NB = (M + SCB - 1) / SCB;   // 782 <= 1024
    const int WM = OUT_DIM * IN_DIM;      // 16384

    // workspace layout
    char* ws = (char*)d_ws;
    size_t o = 0;
    float*     h    = (float*)(ws + o);     o += (size_t)N * OUT_DIM * 4;  // 12.8 MB
    _Float16*  zA   = (_Float16*)(ws + o);  o += (size_t)N * OUT_DIM * 2;  // 6.4 MB
    _Float16*  zB   = (_Float16*)(ws + o);  o += (size_t)N * OUT_DIM * 2;  // 6.4 MB
    float2*    csr  = (float2*)(ws + o);    o += (size_t)E * 8;            // 12.8 MB
    float*     dinv = (float*)(ws + o);     o += (size_t)N * 4;
    int*       off4 = (int*)(ws + o);       o += (size_t)(M + 1) * 4;
    int*       cnt  = (int*)(ws + o);       o += (size_t)M * 4;
    int*       cur  = (int*)(ws + o);       o += (size_t)M * 4;
    int*       bsum = (int*)(ws + o);       o += (size_t)NB * 4;
    int*       boff = (int*)(ws + o);       o += (size_t)NB * 4;
    short*     Wh   = (short*)(ws + o);     o += (size_t)WM * 2;
    short*     Wl   = (short*)(ws + o);     o += (size_t)WM * 2;

    const int B = 256;
    int gN = (N + B - 1) / B;
    int gE = (E + B - 1) / B;
    int gP = ((size_t)N * 4 + B - 1) / B;   // pull grid (1563)
    int gG = (N + 63) / 64;                 // gemm grid (1563)
    int gW = (WM + B - 1) / B;

    hipMemsetAsync(cnt, 0, (size_t)2 * M * 4, stream);  // cnt + cur (adjacent)

    // degree + norm + chunked CSR
    k_count<<<gE, B, 0, stream>>>(src, dst, cnt, E, cdiv);
    k_rsqrt<<<gN, B, 0, stream>>>(cnt, dinv, N);
    k_bsum<<<NB, SCB, 0, stream>>>(cnt, bsum, M);
    k_bscan<<<1, 1024, 0, stream>>>(bsum, boff, off4 + M, NB);
    k_boff<<<NB, SCB, 0, stream>>>(cnt, boff, off4, M);
    k_fill<<<gE, B, 0, stream>>>(src, dst, dinv, off4, cur, csr, E, cdiv);

    // W bf16-split (once) + dense projection (h fp32 + z0 fp16 seed)
    k_wsplit<<<gW, B, 0, stream>>>(W, Wh, Wl, WM);
    k_gemm5<<<gG, B, 0, stream>>>(x, Wh, Wl, bias, h, zA, N);

    // K propagation steps in fp16; final step writes fp32 directly to d_out
    for (int s = 0; s < KSTEPS; s++) {
        const _Float16* zprev = (s % 2 == 0) ? zA : zB;
        _Float16* znext = (s % 2 == 0) ? zB : zA;
        float* outF = (s == KSTEPS - 1) ? (float*)d_out : nullptr;
        k_pull<<<gP, B, 0, stream>>>(off4, csr, zprev, h, dinv, znext, outF, N);
    }
}